// Round 4
// baseline (445.914 us; speedup 1.0000x reference)
//
#include <hip/hip_runtime.h>
#include <hip/hip_bf16.h>
#include <cstdint>

// B=8, N=1024, D=1024, H=16, hd=64, scale=1/8.
// Facts: inputs fp32, output fp32, ws = 64 MiB, threshold 1.47e-3 (bf16
// intermediates give 4.9e-4 — verified every round). R7 swizzled-LDS GEMM
// HW-verified (0 bank conflicts). R9 attn: 32x32x16 MFMA, swapped QK^T,
// in-register P (cvt_pk_bf16 + permlane32_swap), no-max softmax.
// R12: TIME BUDGET showed ~65 us (25%) of inter-launch dead time (sum of
// stages ~187 us vs 255 total; consistent across R0/R1/R3). Fuse the whole
// pipeline into ONE persistent kernel: grid 768 = 3 blocks/CU exactly
// (launch_bounds(256,3) caps regs at 170 >= GEMM's 148 incl AGPR; 32 KB LDS
// union -> 96 KB/CU) so all blocks are co-resident by construction; stages
// separated by a generation grid barrier (device-scope atomicAdd arrivals,
// __hip_atomic_load spin + s_sleep, __threadfence for cross-XCD wb/inv).
// Barrier cells in d_out+16MB (dead until proj GEMM's post-barrier writes;
// memset node re-zeroes per replay). Stage bodies = R3 code verbatim;
// virtual-block stride 768 preserves XCD affinity (768 % 8/16/24 == 0).

typedef __attribute__((ext_vector_type(8))) short short8;   // 8 bf16
typedef __attribute__((ext_vector_type(4))) float floatx4;  // 16x16 MFMA acc
typedef __attribute__((ext_vector_type(16))) float f32x16;  // 32x32 MFMA acc
typedef __attribute__((ext_vector_type(2))) unsigned int uint2v;

__device__ __forceinline__ ushort f2bf(float f) {
    union { float f; uint32_t i; } v; v.f = f;
    uint32_t r = v.i + 0x7fffu + ((v.i >> 16) & 1u);  // RNE
    return (ushort)(r >> 16);
}
__device__ __forceinline__ uint32_t pack2(float a, float b) {
    return (uint32_t)f2bf(a) | ((uint32_t)f2bf(b) << 16);
}
__device__ __forceinline__ uint32_t cvtpk_bf16(float a, float b) {
    uint32_t r;
    asm("v_cvt_pk_bf16_f32 %0, %1, %2" : "=v"(r) : "v"(a), "v"(b));
    return r;  // low16 = bf16(a), high16 = bf16(b)
}
__device__ __forceinline__ void gl2lds16(const void* g, void* lds) {
    __builtin_amdgcn_global_load_lds(
        (const __attribute__((address_space(1))) uint32_t*)(uintptr_t)g,
        (__attribute__((address_space(3))) uint32_t*)(uintptr_t)lds,
        16, 0, 0);
}

// ---------------------------------------------------------------------------
// Grid barrier (generation-based). All NB blocks co-resident by capacity
// arithmetic. Arrivals: device-scope atomicAdd (m20). Spin: atomic LOAD
// (not RMW -> no coherence-point serialization) + s_sleep. __threadfence =
// agent-scope wbl2/inv (cross-XCD visibility both directions).
// ---------------------------------------------------------------------------
__device__ __forceinline__ void gridbar(unsigned* cnt, unsigned nblk) {
    unsigned* gen = cnt + 32;   // 128 B apart
    __syncthreads();            // drains each wave's stores (vmcnt(0))
    if (threadIdx.x == 0) {
        __threadfence();        // release: wb this XCD's L2 to device scope
        unsigned g = __hip_atomic_load(gen, __ATOMIC_RELAXED,
                                       __HIP_MEMORY_SCOPE_AGENT);
        if (atomicAdd(cnt, 1u) == nblk - 1u) {
            atomicExch(cnt, 0u);
            __threadfence();    // order reset before release
            atomicAdd(gen, 1u);
        } else {
            do { __builtin_amdgcn_s_sleep(32); }
            while (__hip_atomic_load(gen, __ATOMIC_RELAXED,
                                     __HIP_MEMORY_SCOPE_AGENT) == g);
        }
        __threadfence();        // acquire: inv L1 + stale L2 lines
    }
    __syncthreads();
}

// ---------------------------------------------------------------------------
// Stage bodies (R3-proven code, re-indexed to virtual block ids).
// ---------------------------------------------------------------------------
__device__ __forceinline__ void aprep_dev(int vb, const float* __restrict__ in,
                                          ushort* ob) {
    const int i = (vb * 256 + (int)threadIdx.x) * 8;
    const float4 f0 = *(const float4*)&in[i];
    const float4 f1 = *(const float4*)&in[i + 4];
    uint4 pk;
    pk.x = pack2(f0.x, f0.y); pk.y = pack2(f0.z, f0.w);
    pk.z = pack2(f1.x, f1.y); pk.w = pack2(f1.z, f1.w);
    *(uint4*)&ob[i] = pk;
}

__device__ __forceinline__ void wprep_dev(ushort* SM, int k0, int n0,
                                          const float* __restrict__ W,
                                          ushort* WT, int K, int N) {
    ushort* T = SM;             // 64*72 ushorts
    const int tid = threadIdx.x;
    __syncthreads();            // T reused across virtual iterations
#pragma unroll
    for (int i = 0; i < 4; ++i) {
        int c = tid + i * 256;
        int kl = c >> 4, n4 = (c & 15) << 2;
        const float4 f = *(const float4*)&W[(size_t)(k0 + kl) * N + n0 + n4];
        T[(n4 + 0) * 72 + kl] = f2bf(f.x);
        T[(n4 + 1) * 72 + kl] = f2bf(f.y);
        T[(n4 + 2) * 72 + kl] = f2bf(f.z);
        T[(n4 + 3) * 72 + kl] = f2bf(f.w);
    }
    __syncthreads();
#pragma unroll
    for (int i = 0; i < 2; ++i) {
        int c = tid + i * 256;
        int nl = c >> 3, k8 = (c & 7) << 3;
        *(uint4*)&WT[(size_t)(n0 + nl) * K + k0 + k8] =
            *(const uint4*)&T[nl * 72 + k8];
    }
}

// BT-GEMM 128x128, BK=64, swizzled unpadded LDS (0 conflicts, HW-verified).
// MODE 0: row-major OutT store. MODE 1: QKV scatter (V transposed).
template <int MODE, typename OutT>
__device__ __forceinline__ void gemm_dev(
    ushort* SM, int bx, int by, const ushort* __restrict__ A,
    const ushort* __restrict__ BT, const float* __restrict__ bias, OutT* C,
    ushort* qb, ushort* kb, ushort* vb, int Nn, int K) {
    ushort* As = SM;            // 8192 ushorts
    ushort* Bs = SM + 8192;     // 8192 ushorts
    const int tid = threadIdx.x;
    const int lane = tid & 63, w = tid >> 6;
    const int wm = w & 1, wn = w >> 1;
    const int l16 = lane & 15, quad = lane >> 4;
    const int m0 = by * 128, n0 = bx * 128;
    const int srow = lane >> 3;
    const int cg = (lane & 7) ^ srow;
    const int sx = l16 & 7;

    floatx4 acc[4][4];
#pragma unroll
    for (int i = 0; i < 4; ++i)
#pragma unroll
        for (int j = 0; j < 4; ++j) acc[i][j] = (floatx4)0.f;

    const int nkt = K >> 6;
    for (int kt = 0; kt < nkt; ++kt) {
        __syncthreads();
#pragma unroll
        for (int i = 0; i < 4; ++i) {
            const int row = w * 32 + i * 8 + srow;
            gl2lds16(&BT[(size_t)(n0 + row) * K + kt * 64 + cg * 8],
                     &Bs[(w * 32 + i * 8) * 64]);
            gl2lds16(&A[(size_t)(m0 + row) * K + kt * 64 + cg * 8],
                     &As[(w * 32 + i * 8) * 64]);
        }
        __syncthreads();
#pragma unroll
        for (int kk = 0; kk < 2; ++kk) {
            const int sl = ((kk << 2) | quad) ^ sx;
            short8 af[4], bfr[4];
#pragma unroll
            for (int mi = 0; mi < 4; ++mi)
                af[mi] = *(const short8*)&As[(wm * 64 + mi * 16 + l16) * 64 +
                                             sl * 8];
#pragma unroll
            for (int ni = 0; ni < 4; ++ni)
                bfr[ni] = *(const short8*)&Bs[(wn * 64 + ni * 16 + l16) * 64 +
                                              sl * 8];
#pragma unroll
            for (int mi = 0; mi < 4; ++mi)
#pragma unroll
                for (int ni = 0; ni < 4; ++ni)
                    acc[mi][ni] = __builtin_amdgcn_mfma_f32_16x16x32_bf16(
                        af[mi], bfr[ni], acc[mi][ni], 0, 0, 0);
        }
    }

#pragma unroll
    for (int mi = 0; mi < 4; ++mi) {
#pragma unroll
        for (int ni = 0; ni < 4; ++ni) {
            const int jg = n0 + wn * 64 + ni * 16 + l16;
            const float bv = bias[jg];
#pragma unroll
            for (int r = 0; r < 4; ++r) {
                const int mg = m0 + wm * 64 + mi * 16 + quad * 4 + r;
                const float vout = acc[mi][ni][r] + bv;
                if (MODE == 0) {
                    if (sizeof(OutT) == 4)
                        ((float*)C)[(size_t)mg * Nn + jg] = vout;
                    else
                        ((ushort*)C)[(size_t)mg * Nn + jg] = f2bf(vout);
                } else {
                    const int which = jg >> 10;
                    const int h = (jg & 1023) >> 6;
                    const int d = jg & 63;
                    const int bb = mg >> 10, nn = mg & 1023;
                    if (which == 0)
                        qb[(size_t)((bb * 16 + h) * 1024 + nn) * 64 + d] =
                            f2bf(vout);
                    else if (which == 1)
                        kb[(size_t)((bb * 16 + h) * 1024 + nn) * 64 + d] =
                            f2bf(vout);
                    else  // V pre-transposed: [B,H,hd,N]
                        vb[((size_t)(bb * 16 + h) * 64 + d) * 1024 + nn] =
                            f2bf(vout);
                }
            }
        }
    }
}

// Flash attention (R9/R11): 32x32x16 MFMA, swapped QK^T, in-register P.
__device__ __forceinline__ void attn_dev(ushort* SM, int h, int qt, int b,
                                         const ushort* q, const ushort* k,
                                         const ushort* v, ushort* o) {
    ushort* Qs = SM;            // 8192 ushorts
    ushort* Ks = SM + 8192;     // 4096
    ushort* VTs = SM + 12288;   // 4096  VT[d][key]
    const int tid = threadIdx.x;
    const int lane = tid & 63, w = tid >> 6;
    const int l31 = lane & 31, hi = lane >> 5, l7 = lane & 7;
    const size_t head_off = (size_t)(b * 16 + h) * 1024 * 64;
    const ushort* Qp = q + head_off + (size_t)qt * 128 * 64;
    const ushort* Vp = v + head_off;     // [64 d][1024 key]
    const int srow = lane >> 3;
    const int cg = (lane & 7) ^ srow;
    const float CEXP = 0.125f * 1.44269504f;  // scale * log2(e)

#pragma unroll
    for (int g = 0; g < 4; ++g)
        gl2lds16(&Qp[(size_t)(w * 32 + g * 8 + srow) * 64 + cg * 8],
                 &Qs[(w * 32 + g * 8) * 64]);
    __syncthreads();

    // Q fragment (B-operand of swapped QK^T): col=q=lane&31, k=hd c*16+hi*8+j
    short8 bq[4];
#pragma unroll
    for (int c = 0; c < 4; ++c)
        bq[c] = *(const short8*)&Qs[(w * 32 + l31) * 64 +
                                    ((2 * c + hi) ^ l7) * 8];

    f32x16 oacc[2];
    oacc[0] = (f32x16)0.f;
    oacc[1] = (f32x16)0.f;
    float ls = 0.f;

    for (int kt = 0; kt < 16; ++kt) {
        __syncthreads();
        const ushort* Kp = k + head_off + (size_t)kt * 64 * 64;
#pragma unroll
        for (int g = 0; g < 2; ++g) {
            gl2lds16(&Kp[(size_t)(w * 16 + g * 8 + srow) * 64 + cg * 8],
                     &Ks[(w * 16 + g * 8) * 64]);
            gl2lds16(&Vp[(size_t)(w * 16 + g * 8 + srow) * 1024 +
                         kt * 64 + cg * 8],
                     &VTs[(w * 16 + g * 8) * 64]);
        }
        __syncthreads();

#pragma unroll
        for (int st = 0; st < 2; ++st) {
            // S^T = K_st * Q^T : A=K rows (key), B=Q rows (q)
            f32x16 sacc = (f32x16)0.f;
            __builtin_amdgcn_s_setprio(1);
#pragma unroll
            for (int c = 0; c < 4; ++c) {
                short8 ak = *(const short8*)&Ks[(st * 32 + l31) * 64 +
                                                ((2 * c + hi) ^ l7) * 8];
                sacc = __builtin_amdgcn_mfma_f32_32x32x16_bf16(
                    ak, bq[c], sacc, 0, 0, 0);
            }
            __builtin_amdgcn_s_setprio(0);
            // sacc[r] = S[key = st*32 + (r&3)+8*(r>>2)+4*hi][q = w*32+l31]
            uint32_t wd[8];
#pragma unroll
            for (int i = 0; i < 8; ++i) {
                const float e0 = __builtin_amdgcn_exp2f(sacc[2 * i] * CEXP);
                const float e1 = __builtin_amdgcn_exp2f(sacc[2 * i + 1] * CEXP);
                ls += e0 + e1;
                wd[i] = cvtpk_bf16(e0, e1);  // keys {base, base+1}
            }
            // permlane32_swap: ret[0]={vdst.lo,vsrc.lo}, ret[1]={vdst.hi,vsrc.hi}
            short8 ap[2];
#pragma unroll
            for (int c2 = 0; c2 < 2; ++c2) {
                uint2v sA = __builtin_amdgcn_permlane32_swap(
                    wd[4 * c2 + 0], wd[4 * c2 + 2], false, false);
                uint2v sB = __builtin_amdgcn_permlane32_swap(
                    wd[4 * c2 + 1], wd[4 * c2 + 3], false, false);
                union { uint32_t u[4]; short8 s; } t;
                t.u[0] = sA[0]; t.u[1] = sB[0];
                t.u[2] = sA[1]; t.u[3] = sB[1];
                ap[c2] = t.s;  // A[row=q=l31][k = c2*16 + hi*8 + j]
            }
            // O += P V : B = VT rows (d), k = key
            __builtin_amdgcn_s_setprio(1);
#pragma unroll
            for (int dt = 0; dt < 2; ++dt)
#pragma unroll
                for (int c2 = 0; c2 < 2; ++c2) {
                    short8 bv = *(const short8*)&VTs[
                        (dt * 32 + l31) * 64 +
                        ((st * 4 + c2 * 2 + hi) ^ l7) * 8];
                    oacc[dt] = __builtin_amdgcn_mfma_f32_32x32x16_bf16(
                        ap[c2], bv, oacc[dt], 0, 0, 0);
                }
            __builtin_amdgcn_s_setprio(0);
        }
    }

    ls += __shfl_xor(ls, 32, 64);
    const float inv = 1.f / ls;

    // oacc[dt][r]: O[q = w*32 + (r&3)+8*(r>>2)+4*hi][d = dt*32 + l31]
#pragma unroll
    for (int r = 0; r < 16; ++r) {
        const int qout = (r & 3) + ((r >> 2) << 3) + (hi << 2);
        const float iq = __shfl(inv, qout, 64);
        const int n = qt * 128 + w * 32 + qout;
#pragma unroll
        for (int dt = 0; dt < 2; ++dt)
            o[((size_t)(b * 1024 + n)) * 1024 + h * 64 + dt * 32 + l31] =
                f2bf(oacc[dt][r] * iq);
    }
}

// ---------------------------------------------------------------------------
// Persistent fused pipeline. 768 blocks x 256 thr = 3 blocks/CU exactly
// (co-resident: regs capped 170 >= 148; LDS 3x32KB = 96 <= 160 KiB).
// Virtual-block stride 768 (== 0 mod 8/16/24) preserves XCD affinity and
// per-block B-panel reuse of the original grids.
// ---------------------------------------------------------------------------
__global__ __launch_bounds__(256, 3)
void mega(const float* __restrict__ inp, const float* __restrict__ w_qkv,
          const float* __restrict__ b_qkv, const float* __restrict__ w_proj,
          const float* __restrict__ b_proj, float* out,
          ushort* qb, ushort* kb, ushort* vbT, ushort* ob,
          ushort* wqkvT, ushort* wprojT, ushort* abf, unsigned* bar) {
    __shared__ ushort SM[16384];   // 32 KiB union for all stages
    const int NB = 768;
    const int r = blockIdx.x;

    // P: A fp32->bf16 (4096 vb) + w_qkv -> wqkvT (768 vb)
    for (int vb = r; vb < 4864; vb += NB) {
        if (vb < 4096) aprep_dev(vb, inp, abf);
        else {
            const int wb = vb - 4096;
            wprep_dev(SM, (wb / 48) * 64, (wb % 48) * 64, w_qkv, wqkvT,
                      1024, 3072);
        }
    }
    gridbar(bar, NB);

    // G1: QKV GEMM 1536 vb (2 even rounds; bx invariant per block)
    for (int vb = r; vb < 1536; vb += NB)
        gemm_dev<1, ushort>(SM, vb % 24, vb / 24, abf, wqkvT, b_qkv,
                            (ushort*)nullptr, qb, kb, vbT, 3072, 1024);
    gridbar(bar, NB);

    // A: attention 2048 vb; h = vb&15 invariant per block -> head/XCD affinity
    for (int vb = r; vb < 2048; vb += NB)
        attn_dev(SM, vb & 15, (vb >> 4) & 7, vb >> 7, qb, kb, vbT, ob);
    gridbar(bar, NB);

    // W2: w_proj -> wprojT (into dead qb region), 256 vb
    for (int vb = r; vb < 256; vb += NB)
        wprep_dev(SM, (vb / 16) * 64, (vb % 16) * 64, w_proj, wprojT,
                  1024, 1024);
    gridbar(bar, NB);

    // G2: proj GEMM 512 vb -> fp32 out (overwrites abf scratch + bar cells,
    // both dead after the last barrier)
    for (int vb = r; vb < 512; vb += NB)
        gemm_dev<0, float>(SM, vb % 8, vb / 8, ob, wprojT, b_proj, out,
                           nullptr, nullptr, nullptr, 1024, 1024);
}

// ---------------------------------------------------------------------------
extern "C" void kernel_launch(void* const* d_in, const int* in_sizes, int n_in,
                              void* d_out, int out_size, void* d_ws,
                              size_t ws_size, hipStream_t stream) {
    const void *inp = d_in[0], *w_qkv = d_in[1], *b_qkv = d_in[2],
               *w_proj = d_in[3], *b_proj = d_in[4];
    for (int i = 0; i < n_in; ++i) {
        switch (in_sizes[i]) {
            case 8 * 1024 * 1024: inp    = d_in[i]; break;
            case 3 * 1024 * 1024: w_qkv  = d_in[i]; break;
            case 3072:            b_qkv  = d_in[i]; break;
            case 1024 * 1024:     w_proj = d_in[i]; break;
            case 1024:            b_proj = d_in[i]; break;
        }
    }
    float* out = (float*)d_out;

    // ws (64 MiB): [0,16M) qb -> later wprojT; [16,32M) kb; [32,48M) vbT;
    // [48,64M) ob, whose first 6.3 MB first hosts wqkvT (dead before attn).
    // d_out (32 MB): [0,16M) bf16-A scratch (dead after G1); bar cells at
    // +16M (dead after barrier 4); G2 overwrites all of d_out at the end.
    char* ws = (char*)d_ws;
    ushort* qb  = (ushort*)(ws);
    ushort* kb  = (ushort*)(ws + (size_t)16 * 1024 * 1024);
    ushort* vbT = (ushort*)(ws + (size_t)32 * 1024 * 1024);
    ushort* ob  = (ushort*)(ws + (size_t)48 * 1024 * 1024);
    ushort* wqkvT  = ob;
    ushort* wprojT = qb;
    ushort* abf = (ushort*)d_out;   // 16 MB bf16 scratch inside d_out
    unsigned* bar = (unsigned*)((char*)d_out + (size_t)16 * 1024 * 1024);

    // zero the barrier cells each replay (graph node; G2 clobbers them later)
    hipMemsetAsync(bar, 0, 256, stream);

    mega<<<768, 256, 0, stream>>>(
        (const float*)inp, (const float*)w_qkv, (const float*)b_qkv,
        (const float*)w_proj, (const float*)b_proj, out,
        qb, kb, vbT, ob, wqkvT, wprojT, abf, bar);
}

// Round 5
// 250.479 us; speedup vs baseline: 1.7802x; 1.7802x over previous
//
#include <hip/hip_runtime.h>
#include <hip/hip_bf16.h>
#include <cstdint>

// B=8, N=1024, D=1024, H=16, hd=64, scale=1/8.
// Facts: inputs fp32, output fp32, ws = 64 MiB, threshold 1.47e-3 (bf16
// intermediates give 4.9e-4 — verified every round). R7 swizzled-LDS GEMM
// HW-verified (0 bank conflicts). R9 attn: 32x32x16 MFMA, swapped QK^T,
// in-register P (cvt_pk_bf16 + permlane32_swap), no-max softmax.
// R10/R12 POST-MORTEM: both fusion attempts (8-phase GEMM; persistent mega
// kernel with grid barriers) regressed. R12 showed per-stage-optimal
// occupancy beats launch-gap elimination: uniform 3 blocks/CU killed G1's
// 6/CU latency hiding (MfmaUtil 24->14.5) and attn ran uneven rounds.
// R13: revert to R3 structure; two independent, attributable changes:
//  (a) attn K/V double-buffer — prefetch kt+1 via gl2lds into the alternate
//      buffer DURING compute of kt (currently load latency sits exposed
//      between two barriers every iteration). LDS stays 32 KB: Qs region is
//      dead after bq register loads and aliases as buffer-1 (one extra
//      barrier after the bq reads makes the overwrite safe). gl2lds counts
//      vmcnt only, so cur-tile ds_reads never wait on the prefetch.
//  (b) XCD-bijective block remap in both GEMMs (1536=8*192, 512=8*64):
//      each XCD gets a contiguous by-chunk -> A-panels single-XCD-resident,
//      staging misses become L2 hits. Correctness-neutral bijection.

typedef __attribute__((ext_vector_type(8))) short short8;   // 8 bf16
typedef __attribute__((ext_vector_type(4))) float floatx4;  // 16x16 MFMA acc
typedef __attribute__((ext_vector_type(16))) float f32x16;  // 32x32 MFMA acc
typedef __attribute__((ext_vector_type(2))) unsigned int uint2v;

__device__ __forceinline__ ushort f2bf(float f) {
    union { float f; uint32_t i; } v; v.f = f;
    uint32_t r = v.i + 0x7fffu + ((v.i >> 16) & 1u);  // RNE
    return (ushort)(r >> 16);
}
__device__ __forceinline__ uint32_t pack2(float a, float b) {
    return (uint32_t)f2bf(a) | ((uint32_t)f2bf(b) << 16);
}
__device__ __forceinline__ uint32_t cvtpk_bf16(float a, float b) {
    uint32_t r;
    asm("v_cvt_pk_bf16_f32 %0, %1, %2" : "=v"(r) : "v"(a), "v"(b));
    return r;  // low16 = bf16(a), high16 = bf16(b)
}
__device__ __forceinline__ void gl2lds16(const void* g, void* lds) {
    __builtin_amdgcn_global_load_lds(
        (const __attribute__((address_space(1))) uint32_t*)(uintptr_t)g,
        (__attribute__((address_space(3))) uint32_t*)(uintptr_t)lds,
        16, 0, 0);
}

// ---------------------------------------------------------------------------
// Fused prep: blocks [0, nA) do A fp32->bf16 (8 floats/thread);
// blocks [nA, nA+768) transpose w_qkv fp32 [1024,3072] -> wqkvT bf16
// [3072,1024]. One launch instead of two.
// ---------------------------------------------------------------------------
__global__ __launch_bounds__(256)
void prep_fused(const float* __restrict__ in, ushort* __restrict__ ob,
                const float* __restrict__ W, ushort* __restrict__ WT,
                int nA) {
    __shared__ ushort T[64 * 72];
    const int tid = threadIdx.x;
    int bx = blockIdx.x;
    if (bx < nA) {
        const int i = (bx * 256 + tid) * 8;
        const float4 f0 = *(const float4*)&in[i];
        const float4 f1 = *(const float4*)&in[i + 4];
        uint4 pk;
        pk.x = pack2(f0.x, f0.y); pk.y = pack2(f0.z, f0.w);
        pk.z = pack2(f1.x, f1.y); pk.w = pack2(f1.z, f1.w);
        *(uint4*)&ob[i] = pk;
        return;
    }
    bx -= nA;                      // 768 blocks -> (x=48, y=16)
    const int K = 1024, N = 3072;
    const int k0 = (bx / 48) * 64, n0 = (bx % 48) * 64;
#pragma unroll
    for (int i = 0; i < 4; ++i) {
        int c = tid + i * 256;
        int kl = c >> 4, n4 = (c & 15) << 2;
        const float4 f = *(const float4*)&W[(size_t)(k0 + kl) * N + n0 + n4];
        T[(n4 + 0) * 72 + kl] = f2bf(f.x);
        T[(n4 + 1) * 72 + kl] = f2bf(f.y);
        T[(n4 + 2) * 72 + kl] = f2bf(f.z);
        T[(n4 + 3) * 72 + kl] = f2bf(f.w);
    }
    __syncthreads();
#pragma unroll
    for (int i = 0; i < 2; ++i) {
        int c = tid + i * 256;
        int nl = c >> 3, k8 = (c & 7) << 3;
        *(uint4*)&WT[(size_t)(n0 + nl) * K + k0 + k8] =
            *(const uint4*)&T[nl * 72 + k8];
    }
}

// ---------------------------------------------------------------------------
// Weight prep: W fp32 [K,N] -> WT bf16 [N,K]. (proj weights; must run after
// attn because wprojT lives in the qb region.)
// ---------------------------------------------------------------------------
__global__ __launch_bounds__(256)
void wprep(const float* __restrict__ W, ushort* __restrict__ WT,
           int K, int N) {
    __shared__ ushort T[64 * 72];
    const int tid = threadIdx.x;
    const int k0 = blockIdx.y * 64, n0 = blockIdx.x * 64;
#pragma unroll
    for (int i = 0; i < 4; ++i) {
        int c = tid + i * 256;
        int kl = c >> 4, n4 = (c & 15) << 2;
        const float4 f = *(const float4*)&W[(size_t)(k0 + kl) * N + n0 + n4];
        T[(n4 + 0) * 72 + kl] = f2bf(f.x);
        T[(n4 + 1) * 72 + kl] = f2bf(f.y);
        T[(n4 + 2) * 72 + kl] = f2bf(f.z);
        T[(n4 + 3) * 72 + kl] = f2bf(f.w);
    }
    __syncthreads();
#pragma unroll
    for (int i = 0; i < 2; ++i) {
        int c = tid + i * 256;
        int nl = c >> 3, k8 = (c & 7) << 3;
        *(uint4*)&WT[(size_t)(n0 + nl) * K + k0 + k8] =
            *(const uint4*)&T[nl * 72 + k8];
    }
}

// ---------------------------------------------------------------------------
// BT-GEMM (all-bf16): C[M,N] = A[M,K]*BT[N,K]^T + bias[N]. BM=BN=128, BK=64.
// Swizzled unpadded LDS (R7 HW-verified: 0 conflicts). Dual global_load_lds.
// MODE 0: row-major OutT store. MODE 1: QKV scatter (V transposed).
// R13: XCD-bijective block remap (grid % 8 == 0 verified at call sites):
// XCD x gets a contiguous by-chunk -> A-panels single-XCD L2-resident.
// ---------------------------------------------------------------------------
template <int MODE, typename OutT>
__global__ __launch_bounds__(256)
void gemm_bt(const ushort* __restrict__ A, const ushort* __restrict__ BT,
             const float* __restrict__ bias, OutT* __restrict__ C,
             ushort* __restrict__ qb, ushort* __restrict__ kb,
             ushort* __restrict__ vb, int M, int Nn, int K) {
    __shared__ ushort As[128 * 64];
    __shared__ ushort Bs[128 * 64];
    const int tid = threadIdx.x;
    const int lane = tid & 63, w = tid >> 6;
    const int wm = w & 1, wn = w >> 1;
    const int l16 = lane & 15, quad = lane >> 4;
    // XCD swizzle: id' = (id&7)*(nwg/8) + id>>3  (bijective, nwg%8==0)
    const int nwg = gridDim.x * gridDim.y;
    int id = blockIdx.y * gridDim.x + blockIdx.x;
    id = (id & 7) * (nwg >> 3) + (id >> 3);
    const int bx = id % gridDim.x, by = id / gridDim.x;
    const int m0 = by * 128, n0 = bx * 128;
    const int srow = lane >> 3;
    const int cg = (lane & 7) ^ srow;
    const int sx = l16 & 7;

    floatx4 acc[4][4];
#pragma unroll
    for (int i = 0; i < 4; ++i)
#pragma unroll
        for (int j = 0; j < 4; ++j) acc[i][j] = (floatx4)0.f;

    const int nkt = K >> 6;
    for (int kt = 0; kt < nkt; ++kt) {
        __syncthreads();
#pragma unroll
        for (int i = 0; i < 4; ++i) {
            const int row = w * 32 + i * 8 + srow;
            gl2lds16(&BT[(size_t)(n0 + row) * K + kt * 64 + cg * 8],
                     &Bs[(w * 32 + i * 8) * 64]);
            gl2lds16(&A[(size_t)(m0 + row) * K + kt * 64 + cg * 8],
                     &As[(w * 32 + i * 8) * 64]);
        }
        __syncthreads();
#pragma unroll
        for (int kk = 0; kk < 2; ++kk) {
            const int sl = ((kk << 2) | quad) ^ sx;
            short8 af[4], bfr[4];
#pragma unroll
            for (int mi = 0; mi < 4; ++mi)
                af[mi] = *(const short8*)&As[(wm * 64 + mi * 16 + l16) * 64 +
                                             sl * 8];
#pragma unroll
            for (int ni = 0; ni < 4; ++ni)
                bfr[ni] = *(const short8*)&Bs[(wn * 64 + ni * 16 + l16) * 64 +
                                              sl * 8];
#pragma unroll
            for (int mi = 0; mi < 4; ++mi)
#pragma unroll
                for (int ni = 0; ni < 4; ++ni)
                    acc[mi][ni] = __builtin_amdgcn_mfma_f32_16x16x32_bf16(
                        af[mi], bfr[ni], acc[mi][ni], 0, 0, 0);
        }
    }

#pragma unroll
    for (int mi = 0; mi < 4; ++mi) {
#pragma unroll
        for (int ni = 0; ni < 4; ++ni) {
            const int jg = n0 + wn * 64 + ni * 16 + l16;
            const float bv = bias[jg];
#pragma unroll
            for (int r = 0; r < 4; ++r) {
                const int mg = m0 + wm * 64 + mi * 16 + quad * 4 + r;
                const float vout = acc[mi][ni][r] + bv;
                if (MODE == 0) {
                    if (sizeof(OutT) == 4)
                        ((float*)C)[(size_t)mg * Nn + jg] = vout;
                    else
                        ((ushort*)C)[(size_t)mg * Nn + jg] = f2bf(vout);
                } else {
                    const int which = jg >> 10;
                    const int h = (jg & 1023) >> 6;
                    const int d = jg & 63;
                    const int bb = mg >> 10, nn = mg & 1023;
                    if (which == 0)
                        qb[(size_t)((bb * 16 + h) * 1024 + nn) * 64 + d] =
                            f2bf(vout);
                    else if (which == 1)
                        kb[(size_t)((bb * 16 + h) * 1024 + nn) * 64 + d] =
                            f2bf(vout);
                    else  // V pre-transposed: [B,H,hd,N]
                        vb[((size_t)(bb * 16 + h) * 64 + d) * 1024 + nn] =
                            f2bf(vout);
                }
            }
        }
    }
}

// ---------------------------------------------------------------------------
// Flash attention (R9/R11 + R13 double-buffer): 32x32x16 MFMA, swapped QK^T,
// in-register P. LDS 32 KB: bufA [0,16K) = Qs, then K/V buffer for odd kt;
// bufB [16K,32K) = K/V buffer for even kt. K at +0, VT at +8KB within a buf.
// Prefetch of kt+1 is issued before compute of kt; the end-of-iter
// __syncthreads (vmcnt 0) drains it after a full compute phase.
// ---------------------------------------------------------------------------
__global__ __launch_bounds__(256, 4)
void attn_kernel(const ushort* __restrict__ q, const ushort* __restrict__ k,
                 const ushort* __restrict__ v, ushort* __restrict__ o) {
    __shared__ ushort SM[16384];
    ushort* bufA = SM;            // Qs initially; K/V buffer for odd kt
    ushort* bufB = SM + 8192;     // K/V buffer for even kt
    const int tid = threadIdx.x;
    const int lane = tid & 63, w = tid >> 6;
    const int l31 = lane & 31, hi = lane >> 5, l7 = lane & 7;
    const int h = blockIdx.x, qt = blockIdx.y, b = blockIdx.z;
    // linear id = h + 16*qt + 128*b -> all 8 q-tiles of a head land on the
    // same XCD (id mod 8 == h&7); per-XCD K/V working set 4 MB = one L2.
    const size_t head_off = (size_t)(b * 16 + h) * 1024 * 64;
    const ushort* Qp = q + head_off + (size_t)qt * 128 * 64;
    const ushort* Kbase = k + head_off;
    const ushort* Vp = v + head_off;     // [64 d][1024 key]
    const int srow = lane >> 3;
    const int cg = (lane & 7) ^ srow;
    const float CEXP = 0.125f * 1.44269504f;  // scale * log2(e)

    // Q -> bufA and K0/V0 -> bufB in one flight
#pragma unroll
    for (int g = 0; g < 4; ++g)
        gl2lds16(&Qp[(size_t)(w * 32 + g * 8 + srow) * 64 + cg * 8],
                 &bufA[(w * 32 + g * 8) * 64]);
#pragma unroll
    for (int g = 0; g < 2; ++g) {
        gl2lds16(&Kbase[(size_t)(w * 16 + g * 8 + srow) * 64 + cg * 8],
                 &bufB[(w * 16 + g * 8) * 64]);
        gl2lds16(&Vp[(size_t)(w * 16 + g * 8 + srow) * 1024 + cg * 8],
                 &bufB[4096 + (w * 16 + g * 8) * 64]);
    }
    __syncthreads();

    // Q fragment (B-operand of swapped QK^T): col=q=lane&31, k=hd c*16+hi*8+j
    short8 bq[4];
#pragma unroll
    for (int c = 0; c < 4; ++c)
        bq[c] = *(const short8*)&bufA[(w * 32 + l31) * 64 +
                                      ((2 * c + hi) ^ l7) * 8];
    __syncthreads();   // all waves done reading Qs -> bufA reusable

    f32x16 oacc[2];
    oacc[0] = (f32x16)0.f;
    oacc[1] = (f32x16)0.f;
    float ls = 0.f;

    for (int kt = 0; kt < 16; ++kt) {
        ushort* cur = (kt & 1) ? bufA : bufB;
        ushort* nxt = (kt & 1) ? bufB : bufA;
        if (kt < 15) {   // prefetch kt+1 into nxt (reads of nxt drained by
                         // the sync at end of iteration kt-1)
            const ushort* Kp = Kbase + (size_t)(kt + 1) * 64 * 64;
#pragma unroll
            for (int g = 0; g < 2; ++g) {
                gl2lds16(&Kp[(size_t)(w * 16 + g * 8 + srow) * 64 + cg * 8],
                         &nxt[(w * 16 + g * 8) * 64]);
                gl2lds16(&Vp[(size_t)(w * 16 + g * 8 + srow) * 1024 +
                             (kt + 1) * 64 + cg * 8],
                         &nxt[4096 + (w * 16 + g * 8) * 64]);
            }
        }
        const ushort* Ks = cur;
        const ushort* VTs = cur + 4096;

#pragma unroll
        for (int st = 0; st < 2; ++st) {
            // S^T = K_st * Q^T : A=K rows (key), B=Q rows (q)
            f32x16 sacc = (f32x16)0.f;
            __builtin_amdgcn_s_setprio(1);
#pragma unroll
            for (int c = 0; c < 4; ++c) {
                short8 ak = *(const short8*)&Ks[(st * 32 + l31) * 64 +
                                                ((2 * c + hi) ^ l7) * 8];
                sacc = __builtin_amdgcn_mfma_f32_32x32x16_bf16(
                    ak, bq[c], sacc, 0, 0, 0);
            }
            __builtin_amdgcn_s_setprio(0);
            // sacc[r] = S[key = st*32 + (r&3)+8*(r>>2)+4*hi][q = w*32+l31]
            uint32_t wd[8];
#pragma unroll
            for (int i = 0; i < 8; ++i) {
                const float e0 = __builtin_amdgcn_exp2f(sacc[2 * i] * CEXP);
                const float e1 = __builtin_amdgcn_exp2f(sacc[2 * i + 1] * CEXP);
                ls += e0 + e1;
                wd[i] = cvtpk_bf16(e0, e1);  // keys {base, base+1}
            }
            // permlane32_swap: ret[0]={vdst.lo,vsrc.lo}, ret[1]={vdst.hi,vsrc.hi}
            short8 ap[2];
#pragma unroll
            for (int c2 = 0; c2 < 2; ++c2) {
                uint2v sA = __builtin_amdgcn_permlane32_swap(
                    wd[4 * c2 + 0], wd[4 * c2 + 2], false, false);
                uint2v sB = __builtin_amdgcn_permlane32_swap(
                    wd[4 * c2 + 1], wd[4 * c2 + 3], false, false);
                union { uint32_t u[4]; short8 s; } t;
                t.u[0] = sA[0]; t.u[1] = sB[0];
                t.u[2] = sA[1]; t.u[3] = sB[1];
                ap[c2] = t.s;  // A[row=q=l31][k = c2*16 + hi*8 + j]
            }
            // O += P V : B = VT rows (d), k = key
            __builtin_amdgcn_s_setprio(1);
#pragma unroll
            for (int dt = 0; dt < 2; ++dt)
#pragma unroll
                for (int c2 = 0; c2 < 2; ++c2) {
                    short8 bv = *(const short8*)&VTs[
                        (dt * 32 + l31) * 64 +
                        ((st * 4 + c2 * 2 + hi) ^ l7) * 8];
                    oacc[dt] = __builtin_amdgcn_mfma_f32_32x32x16_bf16(
                        ap[c2], bv, oacc[dt], 0, 0, 0);
                }
            __builtin_amdgcn_s_setprio(0);
        }
        __syncthreads();  // drains cur reads (all waves) + prefetch vmcnt
    }

    // merge hi-half partial sums: each lane then holds full sum for q=l31
    ls += __shfl_xor(ls, 32, 64);
    const float inv = 1.f / ls;

    // oacc[dt][r]: O[q = w*32 + (r&3)+8*(r>>2)+4*hi][d = dt*32 + l31]
#pragma unroll
    for (int r = 0; r < 16; ++r) {
        const int qout = (r & 3) + ((r >> 2) << 3) + (hi << 2);
        const float iq = __shfl(inv, qout, 64);
        const int n = qt * 128 + w * 32 + qout;
#pragma unroll
        for (int dt = 0; dt < 2; ++dt)
            o[((size_t)(b * 1024 + n)) * 1024 + h * 64 + dt * 32 + l31] =
                f2bf(oacc[dt][r] * iq);
    }
}

// ---------------------------------------------------------------------------
extern "C" void kernel_launch(void* const* d_in, const int* in_sizes, int n_in,
                              void* d_out, int out_size, void* d_ws,
                              size_t ws_size, hipStream_t stream) {
    const void *inp = d_in[0], *w_qkv = d_in[1], *b_qkv = d_in[2],
               *w_proj = d_in[3], *b_proj = d_in[4];
    for (int i = 0; i < n_in; ++i) {
        switch (in_sizes[i]) {
            case 8 * 1024 * 1024: inp    = d_in[i]; break;
            case 3 * 1024 * 1024: w_qkv  = d_in[i]; break;
            case 3072:            b_qkv  = d_in[i]; break;
            case 1024 * 1024:     w_proj = d_in[i]; break;
            case 1024:            b_proj = d_in[i]; break;
        }
    }
    float* out = (float*)d_out;

    // ws (64 MiB): [0,16M) qb -> later wprojT; [16,32M) kb; [32,48M) vbT;
    // [48,64M) ob, whose first 6.3 MB first hosts wqkvT (dead before attn).
    // d_out (32 MB fp32): first 16.8 MB used as bf16-A scratch until the
    // final proj GEMM overwrites all of d_out (proj reads only ws).
    char* ws = (char*)d_ws;
    ushort* qb  = (ushort*)(ws);
    ushort* kb  = (ushort*)(ws + (size_t)16 * 1024 * 1024);
    ushort* vbT = (ushort*)(ws + (size_t)32 * 1024 * 1024);
    ushort* ob  = (ushort*)(ws + (size_t)48 * 1024 * 1024);
    ushort* wqkvT  = ob;
    ushort* wprojT = qb;
    ushort* abf = (ushort*)d_out;   // 16 MB bf16 scratch inside d_out

    // t0: fused prep — inp fp32 -> bf16 (4096 blocks) + w_qkv -> wqkvT
    // (768 blocks) in one launch
    prep_fused<<<4096 + 768, 256, 0, stream>>>(
        (const float*)inp, abf, (const float*)w_qkv, wqkvT, 4096);

    // t1: QKV GEMM (R7 2-phase 128x128, XCD-swizzled; 1536 % 8 == 0)
    gemm_bt<1, ushort><<<dim3(3072 / 128, 8192 / 128), 256, 0, stream>>>(
        abf, wqkvT, (const float*)b_qkv, (ushort*)nullptr, qb, kb, vbT,
        8192, 3072, 1024);

    // t2: attention — grid (h, qt, b): head-major for XCD/L2 locality
    attn_kernel<<<dim3(16, 8, 8), 256, 0, stream>>>(qb, kb, vbT, ob);

    // t2.5: w_proj -> wprojT (into dead qb region)
    wprep<<<dim3(1024 / 64, 1024 / 64), 256, 0, stream>>>(
        (const float*)w_proj, wprojT, 1024, 1024);

    // t3: proj GEMM -> fp32 out (XCD-swizzled; 512 % 8 == 0; reads only ws)
    gemm_bt<0, float><<<dim3(1024 / 128, 8192 / 128), 256, 0, stream>>>(
        ob, wprojT, (const float*)b_proj, out, nullptr, nullptr, nullptr,
        8192, 1024, 1024);
}

// Round 7
// 248.818 us; speedup vs baseline: 1.7921x; 1.0067x over previous
//
#include <hip/hip_runtime.h>
#include <hip/hip_bf16.h>
#include <cstdint>

// B=8, N=1024, D=1024, H=16, hd=64, scale=1/8.
// Facts: inputs fp32, output fp32, ws = 64 MiB, threshold 1.47e-3 (bf16
// intermediates give 4.9e-4 — verified every round). R7 swizzled-LDS GEMM
// HW-verified (0 bank conflicts). R9 attn: 32x32x16 MFMA, swapped QK^T,
// in-register P (cvt_pk_bf16 + permlane32_swap), no-max softmax.
// R13 POST-MORTEM: attn K/V double-buffer = WIN (~55 -> ~32 us). XCD block
// remap in gemm_bt = LOSS (QKV 87.7 -> 106.9 us despite FETCH 72->58.6 MB):
// with gridDim.x % 8 == 0 the NATURAL order already gives each XCD only
// gridDim.x/8 B-panels (768 KB QKV / 256 KB proj, L2-resident); the
// contiguous-by remap made each XCD stream all 6 MB of B through 4 MB L2
// (thrash -> staging latency exposed, MfmaUtil 24->20). Rule: XCD swizzle
// pays only when it SHRINKS the per-XCD resident set below L2.
// R14: revert the remap (both GEMMs back to natural bx,by); keep attn dbuf,
// fused prep, setprio.
// R15: R14 bench was an infra failure (container died twice, no signal);
// resubmitting the identical R14 kernel for clean attribution.

typedef __attribute__((ext_vector_type(8))) short short8;   // 8 bf16
typedef __attribute__((ext_vector_type(4))) float floatx4;  // 16x16 MFMA acc
typedef __attribute__((ext_vector_type(16))) float f32x16;  // 32x32 MFMA acc
typedef __attribute__((ext_vector_type(2))) unsigned int uint2v;

__device__ __forceinline__ ushort f2bf(float f) {
    union { float f; uint32_t i; } v; v.f = f;
    uint32_t r = v.i + 0x7fffu + ((v.i >> 16) & 1u);  // RNE
    return (ushort)(r >> 16);
}
__device__ __forceinline__ uint32_t pack2(float a, float b) {
    return (uint32_t)f2bf(a) | ((uint32_t)f2bf(b) << 16);
}
__device__ __forceinline__ uint32_t cvtpk_bf16(float a, float b) {
    uint32_t r;
    asm("v_cvt_pk_bf16_f32 %0, %1, %2" : "=v"(r) : "v"(a), "v"(b));
    return r;  // low16 = bf16(a), high16 = bf16(b)
}
__device__ __forceinline__ void gl2lds16(const void* g, void* lds) {
    __builtin_amdgcn_global_load_lds(
        (const __attribute__((address_space(1))) uint32_t*)(uintptr_t)g,
        (__attribute__((address_space(3))) uint32_t*)(uintptr_t)lds,
        16, 0, 0);
}

// ---------------------------------------------------------------------------
// Fused prep: blocks [0, nA) do A fp32->bf16 (8 floats/thread);
// blocks [nA, nA+768) transpose w_qkv fp32 [1024,3072] -> wqkvT bf16
// [3072,1024]. One launch instead of two.
// ---------------------------------------------------------------------------
__global__ __launch_bounds__(256)
void prep_fused(const float* __restrict__ in, ushort* __restrict__ ob,
                const float* __restrict__ W, ushort* __restrict__ WT,
                int nA) {
    __shared__ ushort T[64 * 72];
    const int tid = threadIdx.x;
    int bx = blockIdx.x;
    if (bx < nA) {
        const int i = (bx * 256 + tid) * 8;
        const float4 f0 = *(const float4*)&in[i];
        const float4 f1 = *(const float4*)&in[i + 4];
        uint4 pk;
        pk.x = pack2(f0.x, f0.y); pk.y = pack2(f0.z, f0.w);
        pk.z = pack2(f1.x, f1.y); pk.w = pack2(f1.z, f1.w);
        *(uint4*)&ob[i] = pk;
        return;
    }
    bx -= nA;                      // 768 blocks -> (x=48, y=16)
    const int K = 1024, N = 3072;
    const int k0 = (bx / 48) * 64, n0 = (bx % 48) * 64;
#pragma unroll
    for (int i = 0; i < 4; ++i) {
        int c = tid + i * 256;
        int kl = c >> 4, n4 = (c & 15) << 2;
        const float4 f = *(const float4*)&W[(size_t)(k0 + kl) * N + n0 + n4];
        T[(n4 + 0) * 72 + kl] = f2bf(f.x);
        T[(n4 + 1) * 72 + kl] = f2bf(f.y);
        T[(n4 + 2) * 72 + kl] = f2bf(f.z);
        T[(n4 + 3) * 72 + kl] = f2bf(f.w);
    }
    __syncthreads();
#pragma unroll
    for (int i = 0; i < 2; ++i) {
        int c = tid + i * 256;
        int nl = c >> 3, k8 = (c & 7) << 3;
        *(uint4*)&WT[(size_t)(n0 + nl) * K + k0 + k8] =
            *(const uint4*)&T[nl * 72 + k8];
    }
}

// ---------------------------------------------------------------------------
// Weight prep: W fp32 [K,N] -> WT bf16 [N,K]. (proj weights; must run after
// attn because wprojT lives in the qb region.)
// ---------------------------------------------------------------------------
__global__ __launch_bounds__(256)
void wprep(const float* __restrict__ W, ushort* __restrict__ WT,
           int K, int N) {
    __shared__ ushort T[64 * 72];
    const int tid = threadIdx.x;
    const int k0 = blockIdx.y * 64, n0 = blockIdx.x * 64;
#pragma unroll
    for (int i = 0; i < 4; ++i) {
        int c = tid + i * 256;
        int kl = c >> 4, n4 = (c & 15) << 2;
        const float4 f = *(const float4*)&W[(size_t)(k0 + kl) * N + n0 + n4];
        T[(n4 + 0) * 72 + kl] = f2bf(f.x);
        T[(n4 + 1) * 72 + kl] = f2bf(f.y);
        T[(n4 + 2) * 72 + kl] = f2bf(f.z);
        T[(n4 + 3) * 72 + kl] = f2bf(f.w);
    }
    __syncthreads();
#pragma unroll
    for (int i = 0; i < 2; ++i) {
        int c = tid + i * 256;
        int nl = c >> 3, k8 = (c & 7) << 3;
        *(uint4*)&WT[(size_t)(n0 + nl) * K + k0 + k8] =
            *(const uint4*)&T[nl * 72 + k8];
    }
}

// ---------------------------------------------------------------------------
// BT-GEMM (all-bf16): C[M,N] = A[M,K]*BT[N,K]^T + bias[N]. BM=BN=128, BK=64.
// Swizzled unpadded LDS (R7 HW-verified: 0 conflicts). Dual global_load_lds.
// MODE 0: row-major OutT store. MODE 1: QKV scatter (V transposed).
// Natural (bx,by) order — gridDim.x % 8 == 0 makes each XCD's B working set
// gridDim.x/8 panels, L2-resident (R13 lesson: do NOT remap).
// ---------------------------------------------------------------------------
template <int MODE, typename OutT>
__global__ __launch_bounds__(256)
void gemm_bt(const ushort* __restrict__ A, const ushort* __restrict__ BT,
             const float* __restrict__ bias, OutT* __restrict__ C,
             ushort* __restrict__ qb, ushort* __restrict__ kb,
             ushort* __restrict__ vb, int M, int Nn, int K) {
    __shared__ ushort As[128 * 64];
    __shared__ ushort Bs[128 * 64];
    const int tid = threadIdx.x;
    const int lane = tid & 63, w = tid >> 6;
    const int wm = w & 1, wn = w >> 1;
    const int l16 = lane & 15, quad = lane >> 4;
    const int m0 = blockIdx.y * 128, n0 = blockIdx.x * 128;
    const int srow = lane >> 3;
    const int cg = (lane & 7) ^ srow;
    const int sx = l16 & 7;

    floatx4 acc[4][4];
#pragma unroll
    for (int i = 0; i < 4; ++i)
#pragma unroll
        for (int j = 0; j < 4; ++j) acc[i][j] = (floatx4)0.f;

    const int nkt = K >> 6;
    for (int kt = 0; kt < nkt; ++kt) {
        __syncthreads();
#pragma unroll
        for (int i = 0; i < 4; ++i) {
            const int row = w * 32 + i * 8 + srow;
            gl2lds16(&BT[(size_t)(n0 + row) * K + kt * 64 + cg * 8],
                     &Bs[(w * 32 + i * 8) * 64]);
            gl2lds16(&A[(size_t)(m0 + row) * K + kt * 64 + cg * 8],
                     &As[(w * 32 + i * 8) * 64]);
        }
        __syncthreads();
#pragma unroll
        for (int kk = 0; kk < 2; ++kk) {
            const int sl = ((kk << 2) | quad) ^ sx;
            short8 af[4], bfr[4];
#pragma unroll
            for (int mi = 0; mi < 4; ++mi)
                af[mi] = *(const short8*)&As[(wm * 64 + mi * 16 + l16) * 64 +
                                             sl * 8];
#pragma unroll
            for (int ni = 0; ni < 4; ++ni)
                bfr[ni] = *(const short8*)&Bs[(wn * 64 + ni * 16 + l16) * 64 +
                                              sl * 8];
#pragma unroll
            for (int mi = 0; mi < 4; ++mi)
#pragma unroll
                for (int ni = 0; ni < 4; ++ni)
                    acc[mi][ni] = __builtin_amdgcn_mfma_f32_16x16x32_bf16(
                        af[mi], bfr[ni], acc[mi][ni], 0, 0, 0);
        }
    }

#pragma unroll
    for (int mi = 0; mi < 4; ++mi) {
#pragma unroll
        for (int ni = 0; ni < 4; ++ni) {
            const int jg = n0 + wn * 64 + ni * 16 + l16;
            const float bv = bias[jg];
#pragma unroll
            for (int r = 0; r < 4; ++r) {
                const int mg = m0 + wm * 64 + mi * 16 + quad * 4 + r;
                const float vout = acc[mi][ni][r] + bv;
                if (MODE == 0) {
                    if (sizeof(OutT) == 4)
                        ((float*)C)[(size_t)mg * Nn + jg] = vout;
                    else
                        ((ushort*)C)[(size_t)mg * Nn + jg] = f2bf(vout);
                } else {
                    const int which = jg >> 10;
                    const int h = (jg & 1023) >> 6;
                    const int d = jg & 63;
                    const int bb = mg >> 10, nn = mg & 1023;
                    if (which == 0)
                        qb[(size_t)((bb * 16 + h) * 1024 + nn) * 64 + d] =
                            f2bf(vout);
                    else if (which == 1)
                        kb[(size_t)((bb * 16 + h) * 1024 + nn) * 64 + d] =
                            f2bf(vout);
                    else  // V pre-transposed: [B,H,hd,N]
                        vb[((size_t)(bb * 16 + h) * 64 + d) * 1024 + nn] =
                            f2bf(vout);
                }
            }
        }
    }
}

// ---------------------------------------------------------------------------
// Flash attention (R9/R11 + R13 double-buffer): 32x32x16 MFMA, swapped QK^T,
// in-register P. LDS 32 KB: bufA [0,16K) = Qs, then K/V buffer for odd kt;
// bufB [16K,32K) = K/V buffer for even kt. K at +0, VT at +8KB within a buf.
// Prefetch of kt+1 is issued before compute of kt; the end-of-iter
// __syncthreads (vmcnt 0) drains it after a full compute phase.
// ---------------------------------------------------------------------------
__global__ __launch_bounds__(256, 4)
void attn_kernel(const ushort* __restrict__ q, const ushort* __restrict__ k,
                 const ushort* __restrict__ v, ushort* __restrict__ o) {
    __shared__ ushort SM[16384];
    ushort* bufA = SM;            // Qs initially; K/V buffer for odd kt
    ushort* bufB = SM + 8192;     // K/V buffer for even kt
    const int tid = threadIdx.x;
    const int lane = tid & 63, w = tid >> 6;
    const int l31 = lane & 31, hi = lane >> 5, l7 = lane & 7;
    const int h = blockIdx.x, qt = blockIdx.y, b = blockIdx.z;
    // linear id = h + 16*qt + 128*b -> all 8 q-tiles of a head land on the
    // same XCD (id mod 8 == h&7); per-XCD K/V working set 4 MB = one L2.
    const size_t head_off = (size_t)(b * 16 + h) * 1024 * 64;
    const ushort* Qp = q + head_off + (size_t)qt * 128 * 64;
    const ushort* Kbase = k + head_off;
    const ushort* Vp = v + head_off;     // [64 d][1024 key]
    const int srow = lane >> 3;
    const int cg = (lane & 7) ^ srow;
    const float CEXP = 0.125f * 1.44269504f;  // scale * log2(e)

    // Q -> bufA and K0/V0 -> bufB in one flight
#pragma unroll
    for (int g = 0; g < 4; ++g)
        gl2lds16(&Qp[(size_t)(w * 32 + g * 8 + srow) * 64 + cg * 8],
                 &bufA[(w * 32 + g * 8) * 64]);
#pragma unroll
    for (int g = 0; g < 2; ++g) {
        gl2lds16(&Kbase[(size_t)(w * 16 + g * 8 + srow) * 64 + cg * 8],
                 &bufB[(w * 16 + g * 8) * 64]);
        gl2lds16(&Vp[(size_t)(w * 16 + g * 8 + srow) * 1024 + cg * 8],
                 &bufB[4096 + (w * 16 + g * 8) * 64]);
    }
    __syncthreads();

    // Q fragment (B-operand of swapped QK^T): col=q=lane&31, k=hd c*16+hi*8+j
    short8 bq[4];
#pragma unroll
    for (int c = 0; c < 4; ++c)
        bq[c] = *(const short8*)&bufA[(w * 32 + l31) * 64 +
                                      ((2 * c + hi) ^ l7) * 8];
    __syncthreads();   // all waves done reading Qs -> bufA reusable

    f32x16 oacc[2];
    oacc[0] = (f32x16)0.f;
    oacc[1] = (f32x16)0.f;
    float ls = 0.f;

    for (int kt = 0; kt < 16; ++kt) {
        ushort* cur = (kt & 1) ? bufA : bufB;
        ushort* nxt = (kt & 1) ? bufB : bufA;
        if (kt < 15) {   // prefetch kt+1 into nxt (reads of nxt drained by
                         // the sync at end of iteration kt-1)
            const ushort* Kp = Kbase + (size_t)(kt + 1) * 64 * 64;
#pragma unroll
            for (int g = 0; g < 2; ++g) {
                gl2lds16(&Kp[(size_t)(w * 16 + g * 8 + srow) * 64 + cg * 8],
                         &nxt[(w * 16 + g * 8) * 64]);
                gl2lds16(&Vp[(size_t)(w * 16 + g * 8 + srow) * 1024 +
                             (kt + 1) * 64 + cg * 8],
                         &nxt[4096 + (w * 16 + g * 8) * 64]);
            }
        }
        const ushort* Ks = cur;
        const ushort* VTs = cur + 4096;

#pragma unroll
        for (int st = 0; st < 2; ++st) {
            // S^T = K_st * Q^T : A=K rows (key), B=Q rows (q)
            f32x16 sacc = (f32x16)0.f;
            __builtin_amdgcn_s_setprio(1);
#pragma unroll
            for (int c = 0; c < 4; ++c) {
                short8 ak = *(const short8*)&Ks[(st * 32 + l31) * 64 +
                                                ((2 * c + hi) ^ l7) * 8];
                sacc = __builtin_amdgcn_mfma_f32_32x32x16_bf16(
                    ak, bq[c], sacc, 0, 0, 0);
            }
            __builtin_amdgcn_s_setprio(0);
            // sacc[r] = S[key = st*32 + (r&3)+8*(r>>2)+4*hi][q = w*32+l31]
            uint32_t wd[8];
#pragma unroll
            for (int i = 0; i < 8; ++i) {
                const float e0 = __builtin_amdgcn_exp2f(sacc[2 * i] * CEXP);
                const float e1 = __builtin_amdgcn_exp2f(sacc[2 * i + 1] * CEXP);
                ls += e0 + e1;
                wd[i] = cvtpk_bf16(e0, e1);  // keys {base, base+1}
            }
            // permlane32_swap: ret[0]={vdst.lo,vsrc.lo}, ret[1]={vdst.hi,vsrc.hi}
            short8 ap[2];
#pragma unroll
            for (int c2 = 0; c2 < 2; ++c2) {
                uint2v sA = __builtin_amdgcn_permlane32_swap(
                    wd[4 * c2 + 0], wd[4 * c2 + 2], false, false);
                uint2v sB = __builtin_amdgcn_permlane32_swap(
                    wd[4 * c2 + 1], wd[4 * c2 + 3], false, false);
                union { uint32_t u[4]; short8 s; } t;
                t.u[0] = sA[0]; t.u[1] = sB[0];
                t.u[2] = sA[1]; t.u[3] = sB[1];
                ap[c2] = t.s;  // A[row=q=l31][k = c2*16 + hi*8 + j]
            }
            // O += P V : B = VT rows (d), k = key
            __builtin_amdgcn_s_setprio(1);
#pragma unroll
            for (int dt = 0; dt < 2; ++dt)
#pragma unroll
                for (int c2 = 0; c2 < 2; ++c2) {
                    short8 bv = *(const short8*)&VTs[
                        (dt * 32 + l31) * 64 +
                        ((st * 4 + c2 * 2 + hi) ^ l7) * 8];
                    oacc[dt] = __builtin_amdgcn_mfma_f32_32x32x16_bf16(
                        ap[c2], bv, oacc[dt], 0, 0, 0);
                }
            __builtin_amdgcn_s_setprio(0);
        }
        __syncthreads();  // drains cur reads (all waves) + prefetch vmcnt
    }

    // merge hi-half partial sums: each lane then holds full sum for q=l31
    ls += __shfl_xor(ls, 32, 64);
    const float inv = 1.f / ls;

    // oacc[dt][r]: O[q = w*32 + (r&3)+8*(r>>2)+4*hi][d = dt*32 + l31]
#pragma unroll
    for (int r = 0; r < 16; ++r) {
        const int qout = (r & 3) + ((r >> 2) << 3) + (hi << 2);
        const float iq = __shfl(inv, qout, 64);
        const int n = qt * 128 + w * 32 + qout;
#pragma unroll
        for (int dt = 0; dt < 2; ++dt)
            o[((size_t)(b * 1024 + n)) * 1024 + h * 64 + dt * 32 + l31] =
                f2bf(oacc[dt][r] * iq);
    }
}

// ---------------------------------------------------------------------------
extern "C" void kernel_launch(void* const* d_in, const int* in_sizes, int n_in,
                              void* d_out, int out_size, void* d_ws,
                              size_t ws_size, hipStream_t stream) {
    const void *inp = d_in[0], *w_qkv = d_in[1], *b_qkv = d_in[2],
               *w_proj = d_in[3], *b_proj = d_in[4];
    for (int i = 0; i < n_in; ++i) {
        switch (in_sizes[i]) {
            case 8 * 1024 * 1024: inp    = d_in[i]; break;
            case 3 * 1024 * 1024: w_qkv  = d_in[i]; break;
            case 3072:            b_qkv  = d_in[i]; break;
            case 1024 * 1024:     w_proj = d_in[i]; break;
            case 1024:            b_proj = d_in[i]; break;
        }
    }
    float* out = (float*)d_out;

    // ws (64 MiB): [0,16M) qb -> later wprojT; [16,32M) kb; [32,48M) vbT;
    // [48,64M) ob, whose first 6.3 MB first hosts wqkvT (dead before attn).
    // d_out (32 MB fp32): first 16 MB used as bf16-A scratch until the
    // final proj GEMM overwrites all of d_out (proj reads only ws).
    char* ws = (char*)d_ws;
    ushort* qb  = (ushort*)(ws);
    ushort* kb  = (ushort*)(ws + (size_t)16 * 1024 * 1024);
    ushort* vbT = (ushort*)(ws + (size_t)32 * 1024 * 1024);
    ushort* ob  = (ushort*)(ws + (size_t)48 * 1024 * 1024);
    ushort* wqkvT  = ob;
    ushort* wprojT = qb;
    ushort* abf = (ushort*)d_out;   // 16 MB bf16 scratch inside d_out

    // t0: fused prep — inp fp32 -> bf16 (4096 blocks) + w_qkv -> wqkvT
    // (768 blocks) in one launch
    prep_fused<<<4096 + 768, 256, 0, stream>>>(
        (const float*)inp, abf, (const float*)w_qkv, wqkvT, 4096);

    // t1: QKV GEMM (R7 2-phase 128x128, natural block order)
    gemm_bt<1, ushort><<<dim3(3072 / 128, 8192 / 128), 256, 0, stream>>>(
        abf, wqkvT, (const float*)b_qkv, (ushort*)nullptr, qb, kb, vbT,
        8192, 3072, 1024);

    // t2: attention — grid (h, qt, b): head-major for XCD/L2 locality
    attn_kernel<<<dim3(16, 8, 8), 256, 0, stream>>>(qb, kb, vbT, ob);

    // t2.5: w_proj -> wprojT (into dead qb region)
    wprep<<<dim3(1024 / 64, 1024 / 64), 256, 0, stream>>>(
        (const float*)w_proj, wprojT, 1024, 1024);

    // t3: proj GEMM -> fp32 out (natural block order; reads only ws)
    gemm_bt<0, float><<<dim3(1024 / 128, 8192 / 128), 256, 0, stream>>>(
        ob, wprojT, (const float*)b_proj, out, nullptr, nullptr, nullptr,
        8192, 1024, 1024);
}